// Round 10
// baseline (27.268 us; speedup 1.0000x reference)
//
#include <hip/hip_runtime.h>
#include <hip/hip_bf16.h>

// EMD loss: input (N,C,S)=(32,256,4096) fp32, target (N,S) int32.
// out = mean_{n,s}[ sum_c (cumsum_c(input) - [c>=target])^2 / S ]
//
// R9 = R8 (26.7us: float4 16B/lane requests, exact C-split identity) with
// occupancy doubled at the SAME request width: H_SPLIT=8 (CLEN=32),
// 512-thread blocks, 512 blocks = 2 blocks/CU = 16 waves/CU.
// R2's "more waves hurt" was at 4B/lane; R8 proved width was the confound.
// Cross-chunk coupling (exact, verified R2/R3/R8, absmax 0.0):
//   sum_c (P+q-t)^2 = A + 2 P B + CLEN P^2, P = prefix of chunk sums,
//   exchanged via LDS within the block (all 8 chunks of a column co-block).

#define N_DIM 32
#define C_DIM 256
#define S_DIM 4096
#define H_SPLIT 8
#define CLEN (C_DIM / H_SPLIT)     // 32
#define S4 (S_DIM / 4)             // 1024 float4 per row
#define NBLOCKS 512                // 32768 float4-columns / 64 per block
// /S (per-column norm) * /(N*S) (mean) = 1/2^29, exact in fp32
#define SCALE (1.0f / (float)(1u << 29))

typedef float f32x4 __attribute__((ext_vector_type(4)));

__global__ __launch_bounds__(512) void emd_main(
    const f32x4* __restrict__ in4, const int* __restrict__ tgt,
    float* __restrict__ partials)
{
    const int tid  = threadIdx.x;
    const int lane = tid & 63;                 // column slot within block
    const int h    = tid >> 6;                 // chunk id = wave id (0..7)
    const int j4   = blockIdx.x * 64 + lane;   // float4-column in [0, 32768)
    const int n    = j4 >> 10;                 // j4 / S4
    const int s4   = j4 & (S4 - 1);

    const f32x4* p = in4 + ((size_t)(n * C_DIM + h * CLEN)) * S4 + s4;

    const int4 T = reinterpret_cast<const int4*>(tgt)[j4];
    const int Tx = T.x - h * CLEN;
    const int Ty = T.y - h * CLEN;
    const int Tz = T.z - h * CLEN;
    const int Tw = T.w - h * CLEN;

    f32x4 q = (f32x4)(0.f);    // chunk-local cumsum
    f32x4 A = (f32x4)(0.f);    // sum (q-t)^2
    f32x4 B = (f32x4)(0.f);    // sum (q-t)

    #pragma unroll 8
    for (int c = 0; c < CLEN; ++c) {
        const f32x4 v = p[(size_t)c * S4];
        q += v;
        const float d0 = q.x - ((c >= Tx) ? 1.0f : 0.0f);
        const float d1 = q.y - ((c >= Ty) ? 1.0f : 0.0f);
        const float d2 = q.z - ((c >= Tz) ? 1.0f : 0.0f);
        const float d3 = q.w - ((c >= Tw) ? 1.0f : 0.0f);
        A.x = fmaf(d0, d0, A.x);  B.x += d0;
        A.y = fmaf(d1, d1, A.y);  B.y += d1;
        A.z = fmaf(d2, d2, A.z);  B.z += d2;
        A.w = fmaf(d3, d3, A.w);  B.w += d3;
    }

    // exchange chunk sums within the block; P = exclusive prefix over chunks
    __shared__ f32x4 csum[H_SPLIT][64];
    csum[h][lane] = q;
    __syncthreads();

    f32x4 P = (f32x4)(0.f);
    #pragma unroll
    for (int g = 0; g < H_SPLIT - 1; ++g)
        if (g < h) P += csum[g][lane];

    float val = (A.x + A.y + A.z + A.w)
              + 2.0f * (P.x * B.x + P.y * B.y + P.z * B.z + P.w * B.w)
              + (float)CLEN * (P.x * P.x + P.y * P.y + P.z * P.z + P.w * P.w);
    float a = val * SCALE;

    // wave reduce -> per-wave partial -> block partial
    #pragma unroll
    for (int off = 32; off > 0; off >>= 1)
        a += __shfl_down(a, off, 64);

    __shared__ float wpart[H_SPLIT];
    if (lane == 0) wpart[h] = a;
    __syncthreads();
    if (tid == 0) {
        float s = 0.f;
        #pragma unroll
        for (int w = 0; w < H_SPLIT; ++w) s += wpart[w];
        partials[blockIdx.x] = s;
    }
}

__global__ __launch_bounds__(64) void emd_finish(
    const float* __restrict__ partials, float* __restrict__ out)
{
    const int lane = threadIdx.x;
    float a = 0.0f;
    #pragma unroll
    for (int k = 0; k < NBLOCKS / 64; ++k)     // 8 per lane, fixed order
        a += partials[lane + 64 * k];
    #pragma unroll
    for (int off = 32; off > 0; off >>= 1)
        a += __shfl_down(a, off, 64);
    if (lane == 0)
        out[0] = a;
}

extern "C" void kernel_launch(void* const* d_in, const int* in_sizes, int n_in,
                              void* d_out, int out_size, void* d_ws, size_t ws_size,
                              hipStream_t stream) {
    const f32x4* in4 = (const f32x4*)d_in[0];
    const int*   tgt = (const int*)d_in[1];
    float*       out = (float*)d_out;
    float*       partials = (float*)d_ws;    // 512 floats, overwritten each call

    emd_main<<<NBLOCKS, 512, 0, stream>>>(in4, tgt, partials);
    emd_finish<<<1, 64, 0, stream>>>(partials, out);
}